// Round 6
// baseline (1282.918 us; speedup 1.0000x reference)
//
#include <hip/hip_runtime.h>

using u32 = unsigned int;
using u64 = unsigned long long;
using u16 = unsigned short;

typedef __attribute__((ext_vector_type(8))) short bf16x8;
typedef __attribute__((ext_vector_type(4))) float f32x4;

__device__ __forceinline__ u16 f2bf(float f) {
  u32 u = __float_as_uint(f);
  u += 0x7FFFu + ((u >> 16) & 1u);
  return (u16)(u >> 16);
}

__device__ __forceinline__ float wredMaxF(float v) {
#pragma unroll
  for (int o = 32; o > 0; o >>= 1) v = fmaxf(v, __shfl_xor(v, o, 64));
  return v;
}
__device__ __forceinline__ double wredSumD(double v) {
#pragma unroll
  for (int o = 32; o > 0; o >>= 1) v += __shfl_xor(v, o, 64);
  return v;
}
// wave-synchronous LDS ordering: stop compiler motion + drain lgkm
__device__ __forceinline__ void wsync() {
  __builtin_amdgcn_wave_barrier();
  __threadfence_block();
  __builtin_amdgcn_wave_barrier();
}

// K1: q/v 1x1 conv. Query path: exact f64 accumulate -> f32 round, relu, exact f64 t-sum
// kept as f64 (qs64, S1 operand) and f32 (qs32T) for S2 staging.
__global__ __launch_bounds__(256) void k_conv_qv(
    const float* __restrict__ x, const float* __restrict__ qw, const float* __restrict__ qb,
    const float* __restrict__ vw, const float* __restrict__ vb,
    double* __restrict__ qs64, float* __restrict__ qs32T, u16* __restrict__ vr)
{
  __shared__ float Xs[8 * 772];
  __shared__ float wqT[64 * 65];
  __shared__ float wvT[64 * 65];
  __shared__ float qbL[64], vbL[64];
  const int tid = threadIdx.x;
  const int b = blockIdx.y;
  const int n0 = blockIdx.x * 8;

#pragma unroll
  for (int j = 0; j < 16; ++j) {
    int idx = tid + 256 * j;
    int o = idx >> 6, c = idx & 63;
    wqT[c * 65 + o] = qw[idx];
    wvT[c * 65 + o] = vw[idx];
  }
  if (tid < 64) { qbL[tid] = qb[tid]; vbL[tid] = vb[tid]; }
#pragma unroll
  for (int j = 0; j < 6; ++j) {
    int q = tid + 256 * j;
    int pr = q / 3, s = q - pr * 3;
    int c = pr >> 3, nl = pr & 7;
    *(float4*)&Xs[nl * 772 + c * 12 + s * 4] =
        *(const float4*)&x[(((size_t)(b * 64 + c)) * 1024 + n0 + nl) * 12 + s * 4];
  }
  __syncthreads();

  const int co = tid & 63;
  const int nlA = tid >> 6;
  const int nlB = nlA + 4;
  double q0[12], q1[12];
  float v0[12], v1[12];
#pragma unroll
  for (int t = 0; t < 12; ++t) { q0[t] = 0.0; q1[t] = 0.0; v0[t] = 0.f; v1[t] = 0.f; }

  for (int c = 0; c < 64; ++c) {
    double wqv = (double)wqT[c * 65 + co];
    float wvv = wvT[c * 65 + co];
    float xA[12], xB[12];
    *(float4*)&xA[0] = *(float4*)&Xs[nlA * 772 + c * 12 + 0];
    *(float4*)&xA[4] = *(float4*)&Xs[nlA * 772 + c * 12 + 4];
    *(float4*)&xA[8] = *(float4*)&Xs[nlA * 772 + c * 12 + 8];
    *(float4*)&xB[0] = *(float4*)&Xs[nlB * 772 + c * 12 + 0];
    *(float4*)&xB[4] = *(float4*)&Xs[nlB * 772 + c * 12 + 4];
    *(float4*)&xB[8] = *(float4*)&Xs[nlB * 772 + c * 12 + 8];
#pragma unroll
    for (int t = 0; t < 12; ++t) {
      q0[t] = fma(wqv, (double)xA[t], q0[t]);
      q1[t] = fma(wqv, (double)xB[t], q1[t]);
      v0[t] += wvv * xA[t];
      v1[t] += wvv * xB[t];
    }
  }

  const float qbv = qbL[co];
  const float vbv = vbL[co];
  double sA = 0.0, sB = 0.0;
#pragma unroll
  for (int t = 0; t < 12; ++t) {
    float qa = fmaxf((float)q0[t] + qbv, 0.f);
    float qbf = fmaxf((float)q1[t] + qbv, 0.f);
    sA += (double)qa;
    sB += (double)qbf;
  }
  size_t ia = ((size_t)(b * 1024 + n0 + nlA)) * 64 + co;
  size_t ib = ((size_t)(b * 1024 + n0 + nlB)) * 64 + co;
  qs64[ia] = sA; qs64[ib] = sB;
  qs32T[((size_t)(b * 64 + co)) * 1024 + n0 + nlA] = (float)sA;
  qs32T[((size_t)(b * 64 + co)) * 1024 + n0 + nlB] = (float)sB;

  size_t vb0 = ((size_t)(b * 1024 + n0 + nlA)) * 768 + co * 12;
  size_t vb1 = ((size_t)(b * 1024 + n0 + nlB)) * 768 + co * 12;
#pragma unroll
  for (int i = 0; i < 6; ++i) {
    u32 p0 = (u32)f2bf(fmaxf(v0[2 * i] + vbv, 0.f)) | ((u32)f2bf(fmaxf(v0[2 * i + 1] + vbv, 0.f)) << 16);
    *(u32*)&vr[vb0 + 2 * i] = p0;
    u32 p1 = (u32)f2bf(fmaxf(v1[2 * i] + vbv, 0.f)) | ((u32)f2bf(fmaxf(v1[2 * i + 1] + vbv, 0.f)) << 16);
    *(u32*)&vr[vb1 + 2 * i] = p1;
  }
}

// K1b: vr[b][m][ct] -> vrT[b][ct][m]
__global__ __launch_bounds__(256) void k_transpose_vr(const u16* __restrict__ vr, u16* __restrict__ vrT)
{
  __shared__ u16 Tt[64 * 72];
  const int tid = threadIdx.x;
  const int b = blockIdx.z;
  const int ct0 = blockIdx.x * 64;
  const int m0 = blockIdx.y * 64;
#pragma unroll
  for (int j = 0; j < 2; ++j) {
    int idx = tid + 256 * j;
    int r = idx >> 3, s = idx & 7;
    u16 tmp[8];
    *(uint4*)tmp = *(const uint4*)&vr[((size_t)(b * 1024 + m0 + r)) * 768 + ct0 + s * 8];
#pragma unroll
    for (int jj = 0; jj < 8; ++jj) Tt[(s * 8 + jj) * 72 + r] = tmp[jj];
  }
  __syncthreads();
#pragma unroll
  for (int j = 0; j < 2; ++j) {
    int idx = tid + 256 * j;
    int r2 = idx >> 3, s2 = idx & 7;
    *(uint4*)&vrT[((size_t)(b * 768 + ct0 + r2)) * 1024 + m0 + s2 * 8] =
        *(const uint4*)&Tt[r2 * 72 + s2 * 8];
  }
}

// K2: f64-accumulate scores, per-output fma chain over c ascending in 2 phases —
// bit-identical values to R5. Tile 32n x 64m, thread = 1n x 8m, register prefetch,
// 25.9 KB LDS -> 6 blocks/CU.
__global__ __launch_bounds__(256, 6) void k_score(
    const double* __restrict__ qs64, const float* __restrict__ qs32T, const float* __restrict__ mem,
    float* __restrict__ S1, float* __restrict__ S2, int b0)
{
  __shared__ double As64[32 * 33];
  __shared__ float Bm[32 * 68];
  __shared__ float Bq[32 * 68];
  const int tid = threadIdx.x;
  const int g = blockIdx.z;
  const int b = b0 + g;
  const int m0 = blockIdx.x * 64;
  const int n0 = blockIdx.y * 32;

  const int mgi = tid & 7;    // m = m0 + mgi*8 + k
  const int ni  = tid >> 3;   // n = n0 + ni

  double acc1[8], acc2[8];
#pragma unroll
  for (int k = 0; k < 8; ++k) { acc1[k] = 0.0; acc2[k] = 0.0; }

  for (int ph = 0; ph < 2; ++ph) {
    const int cb = ph * 32;
    __syncthreads();
#pragma unroll
    for (int j = 0; j < 4; ++j) {
      int idx = tid + 256 * j;
      int nl = idx >> 5, c = idx & 31;
      As64[nl * 33 + c] = qs64[((size_t)(b * 1024 + n0 + nl)) * 64 + cb + c];
    }
#pragma unroll
    for (int j = 0; j < 8; ++j) {
      int idx = tid + 256 * j;
      int c = idx >> 6, mm = idx & 63;
      Bm[c * 68 + mm] = mem[(size_t)(cb + c) * 1024 + m0 + mm];
      Bq[c * 68 + mm] = qs32T[((size_t)(b * 64 + cb + c)) * 1024 + m0 + mm];
    }
    __syncthreads();

    // register prefetch pipeline over c
    double aP = As64[ni * 33 + 0];
    float4 bmP0 = *(float4*)&Bm[mgi * 8 + 0];
    float4 bmP1 = *(float4*)&Bm[mgi * 8 + 4];
    float4 bqP0 = *(float4*)&Bq[mgi * 8 + 0];
    float4 bqP1 = *(float4*)&Bq[mgi * 8 + 4];
    for (int c = 0; c < 32; ++c) {
      const double aC = aP;
      const float4 bm0 = bmP0, bm1 = bmP1, bq0 = bqP0, bq1 = bqP1;
      if (c < 31) {
        aP = As64[ni * 33 + c + 1];
        bmP0 = *(float4*)&Bm[(c + 1) * 68 + mgi * 8 + 0];
        bmP1 = *(float4*)&Bm[(c + 1) * 68 + mgi * 8 + 4];
        bqP0 = *(float4*)&Bq[(c + 1) * 68 + mgi * 8 + 0];
        bqP1 = *(float4*)&Bq[(c + 1) * 68 + mgi * 8 + 4];
      }
      const double a = aC;
      const double af = (double)(float)aC;   // == np's f32 qs, bit-exact
      float bm8[8] = {bm0.x, bm0.y, bm0.z, bm0.w, bm1.x, bm1.y, bm1.z, bm1.w};
      float bq8[8] = {bq0.x, bq0.y, bq0.z, bq0.w, bq1.x, bq1.y, bq1.z, bq1.w};
#pragma unroll
      for (int k = 0; k < 8; ++k) {
        acc1[k] = fma(a, (double)bm8[k], acc1[k]);
        acc2[k] = fma(af, (double)bq8[k], acc2[k]);
      }
    }
  }
  size_t off = ((size_t)g * 1024 + n0 + ni) * 1024 + m0 + mgi * 8;
  float o1[8], o2[8];
#pragma unroll
  for (int k = 0; k < 8; ++k) {
    o1[k] = fmaxf((float)(0.125 * acc1[k]), 0.f);
    o2[k] = fmaxf((float)(0.125 * acc2[k]), 0.f);
  }
  *(float4*)&S1[off + 0] = *(float4*)&o1[0];
  *(float4*)&S1[off + 4] = *(float4*)&o1[4];
  *(float4*)&S2[off + 0] = *(float4*)&o2[0];
  *(float4*)&S2[off + 4] = *(float4*)&o2[4];
}

// K3: wave-per-row row chain. 4 rows/block, one 64-lane wave each, NO __syncthreads.
__global__ __launch_bounds__(256) void k_row(
    const float* __restrict__ S1, const float* __restrict__ S2,
    const float* __restrict__ fc1w, const float* __restrict__ fc1b,
    const float* __restrict__ fc2w, const float* __restrict__ fc2b,
    u16* __restrict__ adj, int b0)
{
  __shared__ u32 histS[4][256];
  const int tid = threadIdx.x;
  const int wv = tid >> 6;
  const int lane = tid & 63;
  const int n = blockIdx.x * 4 + wv;
  const int g = blockIdx.y;

  float w10[8], w11[8], b1s[8], w2s[8];
#pragma unroll
  for (int h = 0; h < 8; ++h) {
    w10[h] = fc1w[2 * h];
    w11[h] = fc1w[2 * h + 1];
    b1s[h] = fc1b[h];
    w2s[h] = fc2w[h];
  }
  const float b2s = fc2b[0];

  const float* r1 = S1 + ((size_t)g * 1024 + n) * 1024;
  const float* r2 = S2 + ((size_t)g * 1024 + n) * 1024;
  const int e0 = lane * 16;
  float s1v[16], s2v[16];
#pragma unroll
  for (int k = 0; k < 4; ++k) {
    *(float4*)&s1v[4 * k] = *(const float4*)&r1[e0 + 4 * k];
    *(float4*)&s2v[4 * k] = *(const float4*)&r2[e0 + 4 * k];
  }

  float lm1 = s1v[0], lm2 = s2v[0];
#pragma unroll
  for (int j = 1; j < 16; ++j) { lm1 = fmaxf(lm1, s1v[j]); lm2 = fmaxf(lm2, s2v[j]); }
  const float m1 = wredMaxF(lm1);
  const float m2 = wredMaxF(lm2);

  float e1[16], e2[16];
  double ls1 = 0.0, ls2 = 0.0;
#pragma unroll
  for (int j = 0; j < 16; ++j) {
    e1[j] = (float)exp((double)(s1v[j] - m1));
    ls1 += (double)e1[j];
    e2[j] = (float)exp((double)(s2v[j] - m2));
    ls2 += (double)e2[j];
  }
  const float Z1f = (float)wredSumD(ls1);
  const float Z2f = (float)wredSumD(ls2);

  float zv[16];
#pragma unroll
  for (int j = 0; j < 16; ++j) {
    float a1 = e1[j] / Z1f;
    float a2 = e2[j] / Z2f;
    float acc = 0.f;
#pragma unroll
    for (int h = 0; h < 8; ++h) {
      float hp = __fmaf_rn(a2, w11[h], __fmaf_rn(a1, w10[h], 0.0f));
      hp = hp + b1s[h];
      float hr = fmaxf(hp, 0.f);
      acc = __fmaf_rn(hr, w2s[h], acc);
    }
    zv[j] = acc + b2s;
  }

  float lmz = zv[0];
#pragma unroll
  for (int j = 1; j < 16; ++j) lmz = fmaxf(lmz, zv[j]);
  const float mz = wredMaxF(lmz);
  float ez[16];
  double lsz = 0.0;
#pragma unroll
  for (int j = 0; j < 16; ++j) {
    ez[j] = (float)exp((double)(zv[j] - mz));
    lsz += (double)ez[j];
  }
  const float Zzf = (float)wredSumD(lsz);

  u32 kreg[16];
#pragma unroll
  for (int j = 0; j < 16; ++j) kreg[j] = __float_as_uint(ez[j] / Zzf);

  volatile u32* hp = &histS[wv][0];
  u32 target = 819u;
  u32 prefix = 0u;
  for (int pass = 0; pass < 4; ++pass) {
    const int sh = 24 - 8 * pass;
#pragma unroll
    for (int i = 0; i < 4; ++i) hp[4 * lane + i] = 0u;
    wsync();
    if (pass == 0) {
#pragma unroll
      for (int j = 0; j < 16; ++j) {
        u32 bin = kreg[j] >> 24;
        bool pending = true;
        while (true) {
          u64 rem = __ballot(pending);
          if (rem == 0ull) break;
          int ld = (int)__ffsll((long long)rem) - 1;
          u32 fb = __shfl(bin, ld, 64);
          bool mine = pending && (bin == fb);
          u64 grp = __ballot(mine);
          if (lane == ld) atomicAdd((u32*)&hp[fb], (u32)__popcll(grp));
          if (mine) pending = false;
        }
      }
    } else {
#pragma unroll
      for (int j = 0; j < 16; ++j) {
        u32 key = kreg[j];
        if ((key >> (sh + 8)) == prefix) atomicAdd((u32*)&hp[(key >> sh) & 255u], 1u);
      }
    }
    wsync();
    u32 h0 = hp[4 * lane + 0], h1 = hp[4 * lane + 1];
    u32 h2 = hp[4 * lane + 2], h3 = hp[4 * lane + 3];
    u32 part = h0 + h1 + h2 + h3;
    u32 sfx = part;
#pragma unroll
    for (int o = 1; o < 64; o <<= 1) {
      u32 vsh = __shfl_down(sfx, o, 64);
      if (lane + o < 64) sfx += vsh;
    }
    u32 after = sfx - part;
    u32 c3 = h3 + after;
    u32 c2 = h2 + c3;
    u32 c1 = h1 + c2;
    u32 c0 = h0 + c1;
    u32 mybyte = 0u, myabove = 0u;
    bool found = false;
    if (c0 >= target && c1 < target)    { mybyte = (u32)(4 * lane + 0); myabove = c1; found = true; }
    if (c1 >= target && c2 < target)    { mybyte = (u32)(4 * lane + 1); myabove = c2; found = true; }
    if (c2 >= target && c3 < target)    { mybyte = (u32)(4 * lane + 2); myabove = c3; found = true; }
    if (c3 >= target && after < target) { mybyte = (u32)(4 * lane + 3); myabove = after; found = true; }
    u64 fb = __ballot(found);
    int src = (int)__ffsll((long long)fb) - 1;
    u32 byte_ = (u32)__shfl((int)mybyte, src, 64);
    u32 above = (u32)__shfl((int)myabove, src, 64);
    prefix = (prefix << 8) | byte_;
    target -= above;
    wsync();
  }
  const u32 vkey = prefix;
  const u32 need_eq = target;

  int cnt = 0;
#pragma unroll
  for (int j = 0; j < 16; ++j) cnt += (kreg[j] == vkey) ? 1 : 0;
  u32 inc = (u32)cnt;
#pragma unroll
  for (int o = 1; o < 64; o <<= 1) {
    u32 nv = __shfl_up(inc, o, 64);
    if (lane >= o) inc += nv;
  }
  u32 run = inc - (u32)cnt;

  u16 ov[16];
#pragma unroll
  for (int j = 0; j < 16; ++j) {
    u32 kk = kreg[j];
    bool eq = (kk == vkey);
    bool keep = (kk > vkey) || (eq && (run < need_eq));
    if (eq) run += 1u;
    ov[j] = keep ? f2bf(__uint_as_float(kk)) : (u16)0;
  }
  u16* arow = adj + ((size_t)(b0 + g) * 1024 + n) * 1024 + e0;
  *(uint4*)&arow[0] = *(uint4*)&ov[0];
  *(uint4*)&arow[8] = *(uint4*)&ov[8];
}

// K4: agg = adj @ vr, bf16 MFMA 16x16x32, 128x128 tile, BK=32
__global__ __launch_bounds__(256) void k_gemm_agg(
    const u16* __restrict__ adj, const u16* __restrict__ vrT, float* __restrict__ agg)
{
  __shared__ u16 As[128 * 40];
  __shared__ u16 Bs[128 * 40];
  const int tid = threadIdx.x;
  const int b = blockIdx.z;
  const int n0 = blockIdx.y * 128;
  const int ct0 = blockIdx.x * 128;
  const int wid = tid >> 6;
  const int lane = tid & 63;
  const int l16 = lane & 15;
  const int quad = lane >> 4;
  const int wm = (wid >> 1) * 64;
  const int wn = (wid & 1) * 64;

  f32x4 acc[4][4];
#pragma unroll
  for (int i = 0; i < 4; ++i)
#pragma unroll
    for (int j = 0; j < 4; ++j) acc[i][j] = (f32x4)0.f;

  const u16* aG = adj + ((size_t)b * 1024 + n0) * 1024;
  const u16* bG = vrT + ((size_t)b * 768 + ct0) * 1024;

  for (int kt = 0; kt < 32; ++kt) {
    const int k0 = kt * 32;
    __syncthreads();
#pragma unroll
    for (int j = 0; j < 2; ++j) {
      int idx = tid + 256 * j;
      int row = idx >> 2, seg = idx & 3;
      *(uint4*)&As[row * 40 + seg * 8] = *(const uint4*)&aG[(size_t)row * 1024 + k0 + seg * 8];
      *(uint4*)&Bs[row * 40 + seg * 8] = *(const uint4*)&bG[(size_t)row * 1024 + k0 + seg * 8];
    }
    __syncthreads();
    bf16x8 af[4], bfv[4];
#pragma unroll
    for (int i = 0; i < 4; ++i) af[i] = *(bf16x8*)&As[(wm + i * 16 + l16) * 40 + quad * 8];
#pragma unroll
    for (int j = 0; j < 4; ++j) bfv[j] = *(bf16x8*)&Bs[(wn + j * 16 + l16) * 40 + quad * 8];
#pragma unroll
    for (int i = 0; i < 4; ++i)
#pragma unroll
      for (int j = 0; j < 4; ++j)
        acc[i][j] = __builtin_amdgcn_mfma_f32_16x16x32_bf16(af[i], bfv[j], acc[i][j], 0, 0, 0);
  }

#pragma unroll
  for (int i = 0; i < 4; ++i)
#pragma unroll
    for (int j = 0; j < 4; ++j)
#pragma unroll
      for (int r = 0; r < 4; ++r) {
        int row = n0 + wm + i * 16 + quad * 4 + r;
        int col = ct0 + wn + j * 16 + l16;
        agg[((size_t)b * 1024 + row) * 768 + col] = acc[i][j][r];
      }
}

// K5: out = relu(conv_c(agg)), fp32
__global__ __launch_bounds__(256) void k_convc(
    const float* __restrict__ agg, const float* __restrict__ cw,
    const float* __restrict__ cb, float* __restrict__ out)
{
  __shared__ float aggL[16 * 388];
  __shared__ float cwT[64 * 68];
  __shared__ float cbL[64];
  const int tid = threadIdx.x;
  const int b = blockIdx.y;
  const int n0 = blockIdx.x * 16;

#pragma unroll
  for (int j = 0; j < 16; ++j) {
    int idx = tid + 256 * j;
    int o = idx >> 6, c = idx & 63;
    cwT[c * 68 + o] = cw[idx];
  }
  if (tid < 64) cbL[tid] = cb[tid];

  const int o0 = (tid & 15) * 4;
  const int nl = tid >> 4;
  float acc[4][12];
#pragma unroll
  for (int oo = 0; oo < 4; ++oo)
#pragma unroll
    for (int t = 0; t < 12; ++t) acc[oo][t] = 0.f;

  for (int ph = 0; ph < 2; ++ph) {
    __syncthreads();
#pragma unroll
    for (int j = 0; j < 6; ++j) {
      int q4 = tid + 256 * j;
      int row = q4 / 96, wi = q4 - row * 96;
      *(float4*)&aggL[row * 388 + wi * 4] =
          *(const float4*)&agg[((size_t)(b * 1024 + n0 + row)) * 768 + ph * 384 + wi * 4];
    }
    __syncthreads();
    for (int cc = 0; cc < 32; ++cc) {
      int c = ph * 32 + cc;
      float4 w4 = *(float4*)&cwT[c * 68 + o0];
      float xr[12];
      *(float4*)&xr[0] = *(float4*)&aggL[nl * 388 + cc * 12 + 0];
      *(float4*)&xr[4] = *(float4*)&aggL[nl * 388 + cc * 12 + 4];
      *(float4*)&xr[8] = *(float4*)&aggL[nl * 388 + cc * 12 + 8];
#pragma unroll
      for (int t = 0; t < 12; ++t) {
        acc[0][t] += w4.x * xr[t];
        acc[1][t] += w4.y * xr[t];
        acc[2][t] += w4.z * xr[t];
        acc[3][t] += w4.w * xr[t];
      }
    }
  }

#pragma unroll
  for (int oo = 0; oo < 4; ++oo) {
    int o = o0 + oo;
    float bias = cbL[o];
    float ovv[12];
#pragma unroll
    for (int t = 0; t < 12; ++t) ovv[t] = fmaxf(acc[oo][t] + bias, 0.f);
    size_t base = ((size_t)(b * 64 + o) * 1024 + n0 + nl) * 12;
    *(float4*)&out[base + 0] = *(float4*)&ovv[0];
    *(float4*)&out[base + 4] = *(float4*)&ovv[4];
    *(float4*)&out[base + 8] = *(float4*)&ovv[8];
  }
}

extern "C" void kernel_launch(void* const* d_in, const int* in_sizes, int n_in,
                              void* d_out, int out_size, void* d_ws, size_t ws_size,
                              hipStream_t stream)
{
  const float* x    = (const float*)d_in[0];
  const float* qw   = (const float*)d_in[1];
  const float* qb   = (const float*)d_in[2];
  const float* vw   = (const float*)d_in[3];
  const float* vb   = (const float*)d_in[4];
  const float* cw   = (const float*)d_in[5];
  const float* cb   = (const float*)d_in[6];
  const float* mem  = (const float*)d_in[7];
  const float* fc1w = (const float*)d_in[8];
  const float* fc1b = (const float*)d_in[9];
  const float* fc2w = (const float*)d_in[10];
  const float* fc2b = (const float*)d_in[11];
  float* out = (float*)d_out;
  char* ws = (char*)d_ws;

  const size_t szQS64  = (size_t)16 * 1024 * 64 * 8;   // 8 MB
  const size_t szQS32T = (size_t)16 * 1024 * 64 * 4;   // 4 MB
  const size_t szVR    = (size_t)16 * 1024 * 768 * 2;  // 24 MB
  const size_t szADJ   = (size_t)16 * 1024 * 1024 * 2; // 32 MB
  const size_t szAGG   = (size_t)16 * 1024 * 768 * 4;  // 48 MB
  const size_t szSb    = (size_t)1024 * 1024 * 4;      // one f32 S matrix, one batch
  const size_t fixed   = szQS64 + szQS32T + 2 * szVR + szADJ + szAGG;  // 140 MB

  int G = 16;
  while (G > 1 && (fixed + (size_t)2 * G * szSb) > ws_size) G >>= 1;

  double* qs64  = (double*)(ws);
  float*  qs32T = (float*)(ws + szQS64);
  u16*  vr      = (u16*)(ws + szQS64 + szQS32T);
  u16*  vrT     = (u16*)(ws + szQS64 + szQS32T + szVR);
  u16*  adj     = (u16*)(ws + szQS64 + szQS32T + 2 * szVR);
  float* agg    = (float*)(ws + szQS64 + szQS32T + 2 * szVR + szADJ);
  float* S1     = (float*)(ws + fixed);
  float* S2     = S1 + (size_t)G * 1024 * 1024;

  hipLaunchKernelGGL(k_conv_qv, dim3(128, 16), dim3(256), 0, stream, x, qw, qb, vw, vb, qs64, qs32T, vr);
  hipLaunchKernelGGL(k_transpose_vr, dim3(12, 16, 16), dim3(256), 0, stream, vr, vrT);
  for (int b0 = 0; b0 < 16; b0 += G) {
    hipLaunchKernelGGL(k_score, dim3(16, 32, G), dim3(256), 0, stream, qs64, qs32T, mem, S1, S2, b0);
    hipLaunchKernelGGL(k_row, dim3(256, G), dim3(256), 0, stream, S1, S2, fc1w, fc1b, fc2w, fc2b, adj, b0);
  }
  hipLaunchKernelGGL(k_gemm_agg, dim3(6, 8, 16), dim3(256), 0, stream, adj, vrT, agg);
  hipLaunchKernelGGL(k_convc, dim3(64, 16), dim3(256), 0, stream, agg, cw, cb, out);
}

// Round 7
// 654.438 us; speedup vs baseline: 1.9603x; 1.9603x over previous
//
#include <hip/hip_runtime.h>

using u32 = unsigned int;
using u64 = unsigned long long;
using u16 = unsigned short;

typedef __attribute__((ext_vector_type(8))) short bf16x8;
typedef __attribute__((ext_vector_type(4))) float f32x4;

__device__ __forceinline__ u16 f2bf(float f) {
  u32 u = __float_as_uint(f);
  u += 0x7FFFu + ((u >> 16) & 1u);
  return (u16)(u >> 16);
}

__device__ __forceinline__ float wredMaxF(float v) {
#pragma unroll
  for (int o = 32; o > 0; o >>= 1) v = fmaxf(v, __shfl_xor(v, o, 64));
  return v;
}
__device__ __forceinline__ double wredSumD(double v) {
#pragma unroll
  for (int o = 32; o > 0; o >>= 1) v += __shfl_xor(v, o, 64);
  return v;
}
// wave-synchronous LDS ordering: stop compiler motion + drain lgkm
__device__ __forceinline__ void wsync() {
  __builtin_amdgcn_wave_barrier();
  __threadfence_block();
  __builtin_amdgcn_wave_barrier();
}

// K1: q/v 1x1 conv. Query path: exact f64 accumulate -> f32 round, relu, exact f64 t-sum
// kept as f64 (qs64, S1 operand) and f32 (qs32T) for S2 staging.
__global__ __launch_bounds__(256) void k_conv_qv(
    const float* __restrict__ x, const float* __restrict__ qw, const float* __restrict__ qb,
    const float* __restrict__ vw, const float* __restrict__ vb,
    double* __restrict__ qs64, float* __restrict__ qs32T, u16* __restrict__ vr)
{
  __shared__ float Xs[8 * 772];
  __shared__ float wqT[64 * 65];
  __shared__ float wvT[64 * 65];
  __shared__ float qbL[64], vbL[64];
  const int tid = threadIdx.x;
  const int b = blockIdx.y;
  const int n0 = blockIdx.x * 8;

#pragma unroll
  for (int j = 0; j < 16; ++j) {
    int idx = tid + 256 * j;
    int o = idx >> 6, c = idx & 63;
    wqT[c * 65 + o] = qw[idx];
    wvT[c * 65 + o] = vw[idx];
  }
  if (tid < 64) { qbL[tid] = qb[tid]; vbL[tid] = vb[tid]; }
#pragma unroll
  for (int j = 0; j < 6; ++j) {
    int q = tid + 256 * j;
    int pr = q / 3, s = q - pr * 3;
    int c = pr >> 3, nl = pr & 7;
    *(float4*)&Xs[nl * 772 + c * 12 + s * 4] =
        *(const float4*)&x[(((size_t)(b * 64 + c)) * 1024 + n0 + nl) * 12 + s * 4];
  }
  __syncthreads();

  const int co = tid & 63;
  const int nlA = tid >> 6;
  const int nlB = nlA + 4;
  double q0[12], q1[12];
  float v0[12], v1[12];
#pragma unroll
  for (int t = 0; t < 12; ++t) { q0[t] = 0.0; q1[t] = 0.0; v0[t] = 0.f; v1[t] = 0.f; }

  for (int c = 0; c < 64; ++c) {
    double wqv = (double)wqT[c * 65 + co];
    float wvv = wvT[c * 65 + co];
    float xA[12], xB[12];
    *(float4*)&xA[0] = *(float4*)&Xs[nlA * 772 + c * 12 + 0];
    *(float4*)&xA[4] = *(float4*)&Xs[nlA * 772 + c * 12 + 4];
    *(float4*)&xA[8] = *(float4*)&Xs[nlA * 772 + c * 12 + 8];
    *(float4*)&xB[0] = *(float4*)&Xs[nlB * 772 + c * 12 + 0];
    *(float4*)&xB[4] = *(float4*)&Xs[nlB * 772 + c * 12 + 4];
    *(float4*)&xB[8] = *(float4*)&Xs[nlB * 772 + c * 12 + 8];
#pragma unroll
    for (int t = 0; t < 12; ++t) {
      q0[t] = fma(wqv, (double)xA[t], q0[t]);
      q1[t] = fma(wqv, (double)xB[t], q1[t]);
      v0[t] += wvv * xA[t];
      v1[t] += wvv * xB[t];
    }
  }

  const float qbv = qbL[co];
  const float vbv = vbL[co];
  double sA = 0.0, sB = 0.0;
#pragma unroll
  for (int t = 0; t < 12; ++t) {
    float qa = fmaxf((float)q0[t] + qbv, 0.f);
    float qbf = fmaxf((float)q1[t] + qbv, 0.f);
    sA += (double)qa;
    sB += (double)qbf;
  }
  size_t ia = ((size_t)(b * 1024 + n0 + nlA)) * 64 + co;
  size_t ib = ((size_t)(b * 1024 + n0 + nlB)) * 64 + co;
  qs64[ia] = sA; qs64[ib] = sB;
  qs32T[((size_t)(b * 64 + co)) * 1024 + n0 + nlA] = (float)sA;
  qs32T[((size_t)(b * 64 + co)) * 1024 + n0 + nlB] = (float)sB;

  size_t vb0 = ((size_t)(b * 1024 + n0 + nlA)) * 768 + co * 12;
  size_t vb1 = ((size_t)(b * 1024 + n0 + nlB)) * 768 + co * 12;
#pragma unroll
  for (int i = 0; i < 6; ++i) {
    u32 p0 = (u32)f2bf(fmaxf(v0[2 * i] + vbv, 0.f)) | ((u32)f2bf(fmaxf(v0[2 * i + 1] + vbv, 0.f)) << 16);
    *(u32*)&vr[vb0 + 2 * i] = p0;
    u32 p1 = (u32)f2bf(fmaxf(v1[2 * i] + vbv, 0.f)) | ((u32)f2bf(fmaxf(v1[2 * i + 1] + vbv, 0.f)) << 16);
    *(u32*)&vr[vb1 + 2 * i] = p1;
  }
}

// K1b: vr[b][m][ct] -> vrT[b][ct][m]
__global__ __launch_bounds__(256) void k_transpose_vr(const u16* __restrict__ vr, u16* __restrict__ vrT)
{
  __shared__ u16 Tt[64 * 72];
  const int tid = threadIdx.x;
  const int b = blockIdx.z;
  const int ct0 = blockIdx.x * 64;
  const int m0 = blockIdx.y * 64;
#pragma unroll
  for (int j = 0; j < 2; ++j) {
    int idx = tid + 256 * j;
    int r = idx >> 3, s = idx & 7;
    u16 tmp[8];
    *(uint4*)tmp = *(const uint4*)&vr[((size_t)(b * 1024 + m0 + r)) * 768 + ct0 + s * 8];
#pragma unroll
    for (int jj = 0; jj < 8; ++jj) Tt[(s * 8 + jj) * 72 + r] = tmp[jj];
  }
  __syncthreads();
#pragma unroll
  for (int j = 0; j < 2; ++j) {
    int idx = tid + 256 * j;
    int r2 = idx >> 3, s2 = idx & 7;
    *(uint4*)&vrT[((size_t)(b * 768 + ct0 + r2)) * 1024 + m0 + s2 * 8] =
        *(const uint4*)&Tt[r2 * 72 + s2 * 8];
  }
}

// K2: f64-accumulate scores, per-output fma chain over c ascending in 2 phases —
// bit-identical values to R5/R6. Tile 32n x 64m, thread = 1n x 8m, register prefetch,
// 25.5 KB LDS -> 6 blocks/CU.
// NOTE (R6 lesson): do NOT add a min-occupancy launch_bounds arg here — (256,6) capped
// the allocator at 40 VGPRs and spilled the 16 f64 accumulators (WRITE_SIZE 65->612 MB,
// 4x slowdown). Live set needs ~72-84 VGPRs; plain 256 lets LDS set occupancy at 6 blocks.
__global__ __launch_bounds__(256) void k_score(
    const double* __restrict__ qs64, const float* __restrict__ qs32T, const float* __restrict__ mem,
    float* __restrict__ S1, float* __restrict__ S2, int b0)
{
  __shared__ double As64[32 * 33];
  __shared__ float Bm[32 * 68];
  __shared__ float Bq[32 * 68];
  const int tid = threadIdx.x;
  const int g = blockIdx.z;
  const int b = b0 + g;
  const int m0 = blockIdx.x * 64;
  const int n0 = blockIdx.y * 32;

  const int mgi = tid & 7;    // m = m0 + mgi*8 + k
  const int ni  = tid >> 3;   // n = n0 + ni

  double acc1[8], acc2[8];
#pragma unroll
  for (int k = 0; k < 8; ++k) { acc1[k] = 0.0; acc2[k] = 0.0; }

  for (int ph = 0; ph < 2; ++ph) {
    const int cb = ph * 32;
    __syncthreads();
#pragma unroll
    for (int j = 0; j < 4; ++j) {
      int idx = tid + 256 * j;
      int nl = idx >> 5, c = idx & 31;
      As64[nl * 33 + c] = qs64[((size_t)(b * 1024 + n0 + nl)) * 64 + cb + c];
    }
#pragma unroll
    for (int j = 0; j < 8; ++j) {
      int idx = tid + 256 * j;
      int c = idx >> 6, mm = idx & 63;
      Bm[c * 68 + mm] = mem[(size_t)(cb + c) * 1024 + m0 + mm];
      Bq[c * 68 + mm] = qs32T[((size_t)(b * 64 + cb + c)) * 1024 + m0 + mm];
    }
    __syncthreads();

    // register prefetch pipeline over c
    double aP = As64[ni * 33 + 0];
    float4 bmP0 = *(float4*)&Bm[mgi * 8 + 0];
    float4 bmP1 = *(float4*)&Bm[mgi * 8 + 4];
    float4 bqP0 = *(float4*)&Bq[mgi * 8 + 0];
    float4 bqP1 = *(float4*)&Bq[mgi * 8 + 4];
    for (int c = 0; c < 32; ++c) {
      const double aC = aP;
      const float4 bm0 = bmP0, bm1 = bmP1, bq0 = bqP0, bq1 = bqP1;
      if (c < 31) {
        aP = As64[ni * 33 + c + 1];
        bmP0 = *(float4*)&Bm[(c + 1) * 68 + mgi * 8 + 0];
        bmP1 = *(float4*)&Bm[(c + 1) * 68 + mgi * 8 + 4];
        bqP0 = *(float4*)&Bq[(c + 1) * 68 + mgi * 8 + 0];
        bqP1 = *(float4*)&Bq[(c + 1) * 68 + mgi * 8 + 4];
      }
      const double a = aC;
      const double af = (double)(float)aC;   // == np's f32 qs, bit-exact
      float bm8[8] = {bm0.x, bm0.y, bm0.z, bm0.w, bm1.x, bm1.y, bm1.z, bm1.w};
      float bq8[8] = {bq0.x, bq0.y, bq0.z, bq0.w, bq1.x, bq1.y, bq1.z, bq1.w};
#pragma unroll
      for (int k = 0; k < 8; ++k) {
        acc1[k] = fma(a, (double)bm8[k], acc1[k]);
        acc2[k] = fma(af, (double)bq8[k], acc2[k]);
      }
    }
  }
  size_t off = ((size_t)g * 1024 + n0 + ni) * 1024 + m0 + mgi * 8;
  float o1[8], o2[8];
#pragma unroll
  for (int k = 0; k < 8; ++k) {
    o1[k] = fmaxf((float)(0.125 * acc1[k]), 0.f);
    o2[k] = fmaxf((float)(0.125 * acc2[k]), 0.f);
  }
  *(float4*)&S1[off + 0] = *(float4*)&o1[0];
  *(float4*)&S1[off + 4] = *(float4*)&o1[4];
  *(float4*)&S2[off + 0] = *(float4*)&o2[0];
  *(float4*)&S2[off + 4] = *(float4*)&o2[4];
}

// K3: wave-per-row row chain. 4 rows/block, one 64-lane wave each, NO __syncthreads.
__global__ __launch_bounds__(256) void k_row(
    const float* __restrict__ S1, const float* __restrict__ S2,
    const float* __restrict__ fc1w, const float* __restrict__ fc1b,
    const float* __restrict__ fc2w, const float* __restrict__ fc2b,
    u16* __restrict__ adj, int b0)
{
  __shared__ u32 histS[4][256];
  const int tid = threadIdx.x;
  const int wv = tid >> 6;
  const int lane = tid & 63;
  const int n = blockIdx.x * 4 + wv;
  const int g = blockIdx.y;

  float w10[8], w11[8], b1s[8], w2s[8];
#pragma unroll
  for (int h = 0; h < 8; ++h) {
    w10[h] = fc1w[2 * h];
    w11[h] = fc1w[2 * h + 1];
    b1s[h] = fc1b[h];
    w2s[h] = fc2w[h];
  }
  const float b2s = fc2b[0];

  const float* r1 = S1 + ((size_t)g * 1024 + n) * 1024;
  const float* r2 = S2 + ((size_t)g * 1024 + n) * 1024;
  const int e0 = lane * 16;
  float s1v[16], s2v[16];
#pragma unroll
  for (int k = 0; k < 4; ++k) {
    *(float4*)&s1v[4 * k] = *(const float4*)&r1[e0 + 4 * k];
    *(float4*)&s2v[4 * k] = *(const float4*)&r2[e0 + 4 * k];
  }

  float lm1 = s1v[0], lm2 = s2v[0];
#pragma unroll
  for (int j = 1; j < 16; ++j) { lm1 = fmaxf(lm1, s1v[j]); lm2 = fmaxf(lm2, s2v[j]); }
  const float m1 = wredMaxF(lm1);
  const float m2 = wredMaxF(lm2);

  float e1[16], e2[16];
  double ls1 = 0.0, ls2 = 0.0;
#pragma unroll
  for (int j = 0; j < 16; ++j) {
    e1[j] = (float)exp((double)(s1v[j] - m1));
    ls1 += (double)e1[j];
    e2[j] = (float)exp((double)(s2v[j] - m2));
    ls2 += (double)e2[j];
  }
  const float Z1f = (float)wredSumD(ls1);
  const float Z2f = (float)wredSumD(ls2);

  float zv[16];
#pragma unroll
  for (int j = 0; j < 16; ++j) {
    float a1 = e1[j] / Z1f;
    float a2 = e2[j] / Z2f;
    float acc = 0.f;
#pragma unroll
    for (int h = 0; h < 8; ++h) {
      float hp = __fmaf_rn(a2, w11[h], __fmaf_rn(a1, w10[h], 0.0f));
      hp = hp + b1s[h];
      float hr = fmaxf(hp, 0.f);
      acc = __fmaf_rn(hr, w2s[h], acc);
    }
    zv[j] = acc + b2s;
  }

  float lmz = zv[0];
#pragma unroll
  for (int j = 1; j < 16; ++j) lmz = fmaxf(lmz, zv[j]);
  const float mz = wredMaxF(lmz);
  float ez[16];
  double lsz = 0.0;
#pragma unroll
  for (int j = 0; j < 16; ++j) {
    ez[j] = (float)exp((double)(zv[j] - mz));
    lsz += (double)ez[j];
  }
  const float Zzf = (float)wredSumD(lsz);

  u32 kreg[16];
#pragma unroll
  for (int j = 0; j < 16; ++j) kreg[j] = __float_as_uint(ez[j] / Zzf);

  volatile u32* hp = &histS[wv][0];
  u32 target = 819u;
  u32 prefix = 0u;
  for (int pass = 0; pass < 4; ++pass) {
    const int sh = 24 - 8 * pass;
#pragma unroll
    for (int i = 0; i < 4; ++i) hp[4 * lane + i] = 0u;
    wsync();
    if (pass == 0) {
#pragma unroll
      for (int j = 0; j < 16; ++j) {
        u32 bin = kreg[j] >> 24;
        bool pending = true;
        while (true) {
          u64 rem = __ballot(pending);
          if (rem == 0ull) break;
          int ld = (int)__ffsll((long long)rem) - 1;
          u32 fb = __shfl(bin, ld, 64);
          bool mine = pending && (bin == fb);
          u64 grp = __ballot(mine);
          if (lane == ld) atomicAdd((u32*)&hp[fb], (u32)__popcll(grp));
          if (mine) pending = false;
        }
      }
    } else {
#pragma unroll
      for (int j = 0; j < 16; ++j) {
        u32 key = kreg[j];
        if ((key >> (sh + 8)) == prefix) atomicAdd((u32*)&hp[(key >> sh) & 255u], 1u);
      }
    }
    wsync();
    u32 h0 = hp[4 * lane + 0], h1 = hp[4 * lane + 1];
    u32 h2 = hp[4 * lane + 2], h3 = hp[4 * lane + 3];
    u32 part = h0 + h1 + h2 + h3;
    u32 sfx = part;
#pragma unroll
    for (int o = 1; o < 64; o <<= 1) {
      u32 vsh = __shfl_down(sfx, o, 64);
      if (lane + o < 64) sfx += vsh;
    }
    u32 after = sfx - part;
    u32 c3 = h3 + after;
    u32 c2 = h2 + c3;
    u32 c1 = h1 + c2;
    u32 c0 = h0 + c1;
    u32 mybyte = 0u, myabove = 0u;
    bool found = false;
    if (c0 >= target && c1 < target)    { mybyte = (u32)(4 * lane + 0); myabove = c1; found = true; }
    if (c1 >= target && c2 < target)    { mybyte = (u32)(4 * lane + 1); myabove = c2; found = true; }
    if (c2 >= target && c3 < target)    { mybyte = (u32)(4 * lane + 2); myabove = c3; found = true; }
    if (c3 >= target && after < target) { mybyte = (u32)(4 * lane + 3); myabove = after; found = true; }
    u64 fb = __ballot(found);
    int src = (int)__ffsll((long long)fb) - 1;
    u32 byte_ = (u32)__shfl((int)mybyte, src, 64);
    u32 above = (u32)__shfl((int)myabove, src, 64);
    prefix = (prefix << 8) | byte_;
    target -= above;
    wsync();
  }
  const u32 vkey = prefix;
  const u32 need_eq = target;

  int cnt = 0;
#pragma unroll
  for (int j = 0; j < 16; ++j) cnt += (kreg[j] == vkey) ? 1 : 0;
  u32 inc = (u32)cnt;
#pragma unroll
  for (int o = 1; o < 64; o <<= 1) {
    u32 nv = __shfl_up(inc, o, 64);
    if (lane >= o) inc += nv;
  }
  u32 run = inc - (u32)cnt;

  u16 ov[16];
#pragma unroll
  for (int j = 0; j < 16; ++j) {
    u32 kk = kreg[j];
    bool eq = (kk == vkey);
    bool keep = (kk > vkey) || (eq && (run < need_eq));
    if (eq) run += 1u;
    ov[j] = keep ? f2bf(__uint_as_float(kk)) : (u16)0;
  }
  u16* arow = adj + ((size_t)(b0 + g) * 1024 + n) * 1024 + e0;
  *(uint4*)&arow[0] = *(uint4*)&ov[0];
  *(uint4*)&arow[8] = *(uint4*)&ov[8];
}

// K4: agg = adj @ vr, bf16 MFMA 16x16x32, 128x128 tile, BK=32
__global__ __launch_bounds__(256) void k_gemm_agg(
    const u16* __restrict__ adj, const u16* __restrict__ vrT, float* __restrict__ agg)
{
  __shared__ u16 As[128 * 40];
  __shared__ u16 Bs[128 * 40];
  const int tid = threadIdx.x;
  const int b = blockIdx.z;
  const int n0 = blockIdx.y * 128;
  const int ct0 = blockIdx.x * 128;
  const int wid = tid >> 6;
  const int lane = tid & 63;
  const int l16 = lane & 15;
  const int quad = lane >> 4;
  const int wm = (wid >> 1) * 64;
  const int wn = (wid & 1) * 64;

  f32x4 acc[4][4];
#pragma unroll
  for (int i = 0; i < 4; ++i)
#pragma unroll
    for (int j = 0; j < 4; ++j) acc[i][j] = (f32x4)0.f;

  const u16* aG = adj + ((size_t)b * 1024 + n0) * 1024;
  const u16* bG = vrT + ((size_t)b * 768 + ct0) * 1024;

  for (int kt = 0; kt < 32; ++kt) {
    const int k0 = kt * 32;
    __syncthreads();
#pragma unroll
    for (int j = 0; j < 2; ++j) {
      int idx = tid + 256 * j;
      int row = idx >> 2, seg = idx & 3;
      *(uint4*)&As[row * 40 + seg * 8] = *(const uint4*)&aG[(size_t)row * 1024 + k0 + seg * 8];
      *(uint4*)&Bs[row * 40 + seg * 8] = *(const uint4*)&bG[(size_t)row * 1024 + k0 + seg * 8];
    }
    __syncthreads();
    bf16x8 af[4], bfv[4];
#pragma unroll
    for (int i = 0; i < 4; ++i) af[i] = *(bf16x8*)&As[(wm + i * 16 + l16) * 40 + quad * 8];
#pragma unroll
    for (int j = 0; j < 4; ++j) bfv[j] = *(bf16x8*)&Bs[(wn + j * 16 + l16) * 40 + quad * 8];
#pragma unroll
    for (int i = 0; i < 4; ++i)
#pragma unroll
      for (int j = 0; j < 4; ++j)
        acc[i][j] = __builtin_amdgcn_mfma_f32_16x16x32_bf16(af[i], bfv[j], acc[i][j], 0, 0, 0);
  }

#pragma unroll
  for (int i = 0; i < 4; ++i)
#pragma unroll
    for (int j = 0; j < 4; ++j)
#pragma unroll
      for (int r = 0; r < 4; ++r) {
        int row = n0 + wm + i * 16 + quad * 4 + r;
        int col = ct0 + wn + j * 16 + l16;
        agg[((size_t)b * 1024 + row) * 768 + col] = acc[i][j][r];
      }
}

// K5: out = relu(conv_c(agg)), fp32
__global__ __launch_bounds__(256) void k_convc(
    const float* __restrict__ agg, const float* __restrict__ cw,
    const float* __restrict__ cb, float* __restrict__ out)
{
  __shared__ float aggL[16 * 388];
  __shared__ float cwT[64 * 68];
  __shared__ float cbL[64];
  const int tid = threadIdx.x;
  const int b = blockIdx.y;
  const int n0 = blockIdx.x * 16;

#pragma unroll
  for (int j = 0; j < 16; ++j) {
    int idx = tid + 256 * j;
    int o = idx >> 6, c = idx & 63;
    cwT[c * 68 + o] = cw[idx];
  }
  if (tid < 64) cbL[tid] = cb[tid];

  const int o0 = (tid & 15) * 4;
  const int nl = tid >> 4;
  float acc[4][12];
#pragma unroll
  for (int oo = 0; oo < 4; ++oo)
#pragma unroll
    for (int t = 0; t < 12; ++t) acc[oo][t] = 0.f;

  for (int ph = 0; ph < 2; ++ph) {
    __syncthreads();
#pragma unroll
    for (int j = 0; j < 6; ++j) {
      int q4 = tid + 256 * j;
      int row = q4 / 96, wi = q4 - row * 96;
      *(float4*)&aggL[row * 388 + wi * 4] =
          *(const float4*)&agg[((size_t)(b * 1024 + n0 + row)) * 768 + ph * 384 + wi * 4];
    }
    __syncthreads();
    for (int cc = 0; cc < 32; ++cc) {
      int c = ph * 32 + cc;
      float4 w4 = *(float4*)&cwT[c * 68 + o0];
      float xr[12];
      *(float4*)&xr[0] = *(float4*)&aggL[nl * 388 + cc * 12 + 0];
      *(float4*)&xr[4] = *(float4*)&aggL[nl * 388 + cc * 12 + 4];
      *(float4*)&xr[8] = *(float4*)&aggL[nl * 388 + cc * 12 + 8];
#pragma unroll
      for (int t = 0; t < 12; ++t) {
        acc[0][t] += w4.x * xr[t];
        acc[1][t] += w4.y * xr[t];
        acc[2][t] += w4.z * xr[t];
        acc[3][t] += w4.w * xr[t];
      }
    }
  }

#pragma unroll
  for (int oo = 0; oo < 4; ++oo) {
    int o = o0 + oo;
    float bias = cbL[o];
    float ovv[12];
#pragma unroll
    for (int t = 0; t < 12; ++t) ovv[t] = fmaxf(acc[oo][t] + bias, 0.f);
    size_t base = ((size_t)(b * 64 + o) * 1024 + n0 + nl) * 12;
    *(float4*)&out[base + 0] = *(float4*)&ovv[0];
    *(float4*)&out[base + 4] = *(float4*)&ovv[4];
    *(float4*)&out[base + 8] = *(float4*)&ovv[8];
  }
}

extern "C" void kernel_launch(void* const* d_in, const int* in_sizes, int n_in,
                              void* d_out, int out_size, void* d_ws, size_t ws_size,
                              hipStream_t stream)
{
  const float* x    = (const float*)d_in[0];
  const float* qw   = (const float*)d_in[1];
  const float* qb   = (const float*)d_in[2];
  const float* vw   = (const float*)d_in[3];
  const float* vb   = (const float*)d_in[4];
  const float* cw   = (const float*)d_in[5];
  const float* cb   = (const float*)d_in[6];
  const float* mem  = (const float*)d_in[7];
  const float* fc1w = (const float*)d_in[8];
  const float* fc1b = (const float*)d_in[9];
  const float* fc2w = (const float*)d_in[10];
  const float* fc2b = (const float*)d_in[11];
  float* out = (float*)d_out;
  char* ws = (char*)d_ws;

  const size_t szQS64  = (size_t)16 * 1024 * 64 * 8;   // 8 MB
  const size_t szQS32T = (size_t)16 * 1024 * 64 * 4;   // 4 MB
  const size_t szVR    = (size_t)16 * 1024 * 768 * 2;  // 24 MB
  const size_t szADJ   = (size_t)16 * 1024 * 1024 * 2; // 32 MB
  const size_t szAGG   = (size_t)16 * 1024 * 768 * 4;  // 48 MB
  const size_t szSb    = (size_t)1024 * 1024 * 4;      // one f32 S matrix, one batch
  const size_t fixed   = szQS64 + szQS32T + 2 * szVR + szADJ + szAGG;  // 140 MB

  int G = 16;
  while (G > 1 && (fixed + (size_t)2 * G * szSb) > ws_size) G >>= 1;

  double* qs64  = (double*)(ws);
  float*  qs32T = (float*)(ws + szQS64);
  u16*  vr      = (u16*)(ws + szQS64 + szQS32T);
  u16*  vrT     = (u16*)(ws + szQS64 + szQS32T + szVR);
  u16*  adj     = (u16*)(ws + szQS64 + szQS32T + 2 * szVR);
  float* agg    = (float*)(ws + szQS64 + szQS32T + 2 * szVR + szADJ);
  float* S1     = (float*)(ws + fixed);
  float* S2     = S1 + (size_t)G * 1024 * 1024;

  hipLaunchKernelGGL(k_conv_qv, dim3(128, 16), dim3(256), 0, stream, x, qw, qb, vw, vb, qs64, qs32T, vr);
  hipLaunchKernelGGL(k_transpose_vr, dim3(12, 16, 16), dim3(256), 0, stream, vr, vrT);
  for (int b0 = 0; b0 < 16; b0 += G) {
    hipLaunchKernelGGL(k_score, dim3(16, 32, G), dim3(256), 0, stream, qs64, qs32T, mem, S1, S2, b0);
    hipLaunchKernelGGL(k_row, dim3(256, G), dim3(256), 0, stream, S1, S2, fc1w, fc1b, fc2w, fc2b, adj, b0);
  }
  hipLaunchKernelGGL(k_gemm_agg, dim3(6, 8, 16), dim3(256), 0, stream, adj, vrT, agg);
  hipLaunchKernelGGL(k_convc, dim3(64, 16), dim3(256), 0, stream, agg, cw, cb, out);
}

// Round 8
// 569.203 us; speedup vs baseline: 2.2539x; 1.1497x over previous
//
#include <hip/hip_runtime.h>

using u32 = unsigned int;
using u64 = unsigned long long;
using u16 = unsigned short;

typedef __attribute__((ext_vector_type(8))) short bf16x8;
typedef __attribute__((ext_vector_type(4))) float f32x4;

__device__ __forceinline__ u16 f2bf(float f) {
  u32 u = __float_as_uint(f);
  u += 0x7FFFu + ((u >> 16) & 1u);
  return (u16)(u >> 16);
}

__device__ __forceinline__ float wredMaxF(float v) {
#pragma unroll
  for (int o = 32; o > 0; o >>= 1) v = fmaxf(v, __shfl_xor(v, o, 64));
  return v;
}
__device__ __forceinline__ double wredSumD(double v) {
#pragma unroll
  for (int o = 32; o > 0; o >>= 1) v += __shfl_xor(v, o, 64);
  return v;
}
// wave-synchronous LDS ordering: stop compiler motion + drain lgkm
__device__ __forceinline__ void wsync() {
  __builtin_amdgcn_wave_barrier();
  __threadfence_block();
  __builtin_amdgcn_wave_barrier();
}

// K1: q/v 1x1 conv. Query path: exact f64 accumulate -> f32 round, relu, exact f64 t-sum
// kept as f64 (qs64, S1 operand) and f32 (qs32T) for S2 staging.
__global__ __launch_bounds__(256) void k_conv_qv(
    const float* __restrict__ x, const float* __restrict__ qw, const float* __restrict__ qb,
    const float* __restrict__ vw, const float* __restrict__ vb,
    double* __restrict__ qs64, float* __restrict__ qs32T, u16* __restrict__ vr)
{
  __shared__ float Xs[8 * 772];
  __shared__ float wqT[64 * 65];
  __shared__ float wvT[64 * 65];
  __shared__ float qbL[64], vbL[64];
  const int tid = threadIdx.x;
  const int b = blockIdx.y;
  const int n0 = blockIdx.x * 8;

#pragma unroll
  for (int j = 0; j < 16; ++j) {
    int idx = tid + 256 * j;
    int o = idx >> 6, c = idx & 63;
    wqT[c * 65 + o] = qw[idx];
    wvT[c * 65 + o] = vw[idx];
  }
  if (tid < 64) { qbL[tid] = qb[tid]; vbL[tid] = vb[tid]; }
#pragma unroll
  for (int j = 0; j < 6; ++j) {
    int q = tid + 256 * j;
    int pr = q / 3, s = q - pr * 3;
    int c = pr >> 3, nl = pr & 7;
    *(float4*)&Xs[nl * 772 + c * 12 + s * 4] =
        *(const float4*)&x[(((size_t)(b * 64 + c)) * 1024 + n0 + nl) * 12 + s * 4];
  }
  __syncthreads();

  const int co = tid & 63;
  const int nlA = tid >> 6;
  const int nlB = nlA + 4;
  double q0[12], q1[12];
  float v0[12], v1[12];
#pragma unroll
  for (int t = 0; t < 12; ++t) { q0[t] = 0.0; q1[t] = 0.0; v0[t] = 0.f; v1[t] = 0.f; }

  for (int c = 0; c < 64; ++c) {
    double wqv = (double)wqT[c * 65 + co];
    float wvv = wvT[c * 65 + co];
    float xA[12], xB[12];
    *(float4*)&xA[0] = *(float4*)&Xs[nlA * 772 + c * 12 + 0];
    *(float4*)&xA[4] = *(float4*)&Xs[nlA * 772 + c * 12 + 4];
    *(float4*)&xA[8] = *(float4*)&Xs[nlA * 772 + c * 12 + 8];
    *(float4*)&xB[0] = *(float4*)&Xs[nlB * 772 + c * 12 + 0];
    *(float4*)&xB[4] = *(float4*)&Xs[nlB * 772 + c * 12 + 4];
    *(float4*)&xB[8] = *(float4*)&Xs[nlB * 772 + c * 12 + 8];
#pragma unroll
    for (int t = 0; t < 12; ++t) {
      q0[t] = fma(wqv, (double)xA[t], q0[t]);
      q1[t] = fma(wqv, (double)xB[t], q1[t]);
      v0[t] += wvv * xA[t];
      v1[t] += wvv * xB[t];
    }
  }

  const float qbv = qbL[co];
  const float vbv = vbL[co];
  double sA = 0.0, sB = 0.0;
#pragma unroll
  for (int t = 0; t < 12; ++t) {
    float qa = fmaxf((float)q0[t] + qbv, 0.f);
    float qbf = fmaxf((float)q1[t] + qbv, 0.f);
    sA += (double)qa;
    sB += (double)qbf;
  }
  size_t ia = ((size_t)(b * 1024 + n0 + nlA)) * 64 + co;
  size_t ib = ((size_t)(b * 1024 + n0 + nlB)) * 64 + co;
  qs64[ia] = sA; qs64[ib] = sB;
  qs32T[((size_t)(b * 64 + co)) * 1024 + n0 + nlA] = (float)sA;
  qs32T[((size_t)(b * 64 + co)) * 1024 + n0 + nlB] = (float)sB;

  size_t vb0 = ((size_t)(b * 1024 + n0 + nlA)) * 768 + co * 12;
  size_t vb1 = ((size_t)(b * 1024 + n0 + nlB)) * 768 + co * 12;
#pragma unroll
  for (int i = 0; i < 6; ++i) {
    u32 p0 = (u32)f2bf(fmaxf(v0[2 * i] + vbv, 0.f)) | ((u32)f2bf(fmaxf(v0[2 * i + 1] + vbv, 0.f)) << 16);
    *(u32*)&vr[vb0 + 2 * i] = p0;
    u32 p1 = (u32)f2bf(fmaxf(v1[2 * i] + vbv, 0.f)) | ((u32)f2bf(fmaxf(v1[2 * i + 1] + vbv, 0.f)) << 16);
    *(u32*)&vr[vb1 + 2 * i] = p1;
  }
}

// K1b: vr[b][m][ct] -> vrT[b][ct][m]
__global__ __launch_bounds__(256) void k_transpose_vr(const u16* __restrict__ vr, u16* __restrict__ vrT)
{
  __shared__ u16 Tt[64 * 72];
  const int tid = threadIdx.x;
  const int b = blockIdx.z;
  const int ct0 = blockIdx.x * 64;
  const int m0 = blockIdx.y * 64;
#pragma unroll
  for (int j = 0; j < 2; ++j) {
    int idx = tid + 256 * j;
    int r = idx >> 3, s = idx & 7;
    u16 tmp[8];
    *(uint4*)tmp = *(const uint4*)&vr[((size_t)(b * 1024 + m0 + r)) * 768 + ct0 + s * 8];
#pragma unroll
    for (int jj = 0; jj < 8; ++jj) Tt[(s * 8 + jj) * 72 + r] = tmp[jj];
  }
  __syncthreads();
#pragma unroll
  for (int j = 0; j < 2; ++j) {
    int idx = tid + 256 * j;
    int r2 = idx >> 3, s2 = idx & 7;
    *(uint4*)&vrT[((size_t)(b * 768 + ct0 + r2)) * 1024 + m0 + s2 * 8] =
        *(const uint4*)&Tt[r2 * 72 + s2 * 8];
  }
}

// K2: f64-accumulate scores; per-output fma chain over c globally ascending (4 phases of 16)
// — bit-identical S1/S2 to R7. Tile 128n x 64m, thread = 4n x 8m (64 f64 acc),
// 26.1 KB LDS -> 6 blocks/CU. NOTE (R6): no min-occupancy launch_bounds — it spills the
// f64 accumulators to scratch (WRITE_SIZE 65->612 MB signature).
__global__ __launch_bounds__(256) void k_score(
    const double* __restrict__ qs64, const float* __restrict__ qs32T, const float* __restrict__ mem,
    float* __restrict__ S1, float* __restrict__ S2, int b0)
{
  __shared__ double As64[128 * 17];
  __shared__ float Bm[16 * 68];
  __shared__ float Bq[16 * 68];
  const int tid = threadIdx.x;
  const int g = blockIdx.z;
  const int b = b0 + g;
  const int m0 = blockIdx.x * 64;
  const int n0 = blockIdx.y * 128;

  const int mgi  = tid & 7;    // m = m0 + mgi*8 + k
  const int ngrp = tid >> 3;   // n = n0 + ngrp*4 + ni

  double acc1[4][8], acc2[4][8];
#pragma unroll
  for (int i = 0; i < 4; ++i)
#pragma unroll
    for (int k = 0; k < 8; ++k) { acc1[i][k] = 0.0; acc2[i][k] = 0.0; }

  for (int ph = 0; ph < 4; ++ph) {
    const int cb = ph * 16;
    __syncthreads();
#pragma unroll
    for (int j = 0; j < 8; ++j) {
      int idx = tid + 256 * j;
      int nl = idx >> 4, c = idx & 15;
      As64[nl * 17 + c] = qs64[((size_t)(b * 1024 + n0 + nl)) * 64 + cb + c];
    }
#pragma unroll
    for (int j = 0; j < 4; ++j) {
      int idx = tid + 256 * j;
      int c = idx >> 6, mm = idx & 63;
      Bm[c * 68 + mm] = mem[(size_t)(cb + c) * 1024 + m0 + mm];
      Bq[c * 68 + mm] = qs32T[((size_t)(b * 64 + cb + c)) * 1024 + m0 + mm];
    }
    __syncthreads();

    for (int c = 0; c < 16; ++c) {
      double a[4], af[4];
#pragma unroll
      for (int i = 0; i < 4; ++i) {
        a[i] = As64[(ngrp * 4 + i) * 17 + c];
        af[i] = (double)(float)a[i];   // == np's f32 qs, bit-exact
      }
      float bm8[8], bq8[8];
      *(float4*)&bm8[0] = *(float4*)&Bm[c * 68 + mgi * 8 + 0];
      *(float4*)&bm8[4] = *(float4*)&Bm[c * 68 + mgi * 8 + 4];
      *(float4*)&bq8[0] = *(float4*)&Bq[c * 68 + mgi * 8 + 0];
      *(float4*)&bq8[4] = *(float4*)&Bq[c * 68 + mgi * 8 + 4];
#pragma unroll
      for (int k = 0; k < 8; ++k) {
        double bmd = (double)bm8[k];
        double bqd = (double)bq8[k];
#pragma unroll
        for (int i = 0; i < 4; ++i) {
          acc1[i][k] = fma(a[i], bmd, acc1[i][k]);
          acc2[i][k] = fma(af[i], bqd, acc2[i][k]);
        }
      }
    }
  }
#pragma unroll
  for (int ni = 0; ni < 4; ++ni) {
    size_t off = ((size_t)g * 1024 + n0 + ngrp * 4 + ni) * 1024 + m0 + mgi * 8;
    float o1[8], o2[8];
#pragma unroll
    for (int k = 0; k < 8; ++k) {
      o1[k] = fmaxf((float)(0.125 * acc1[ni][k]), 0.f);
      o2[k] = fmaxf((float)(0.125 * acc2[ni][k]), 0.f);
    }
    *(float4*)&S1[off + 0] = *(float4*)&o1[0];
    *(float4*)&S1[off + 4] = *(float4*)&o1[4];
    *(float4*)&S2[off + 0] = *(float4*)&o2[0];
    *(float4*)&S2[off + 4] = *(float4*)&o2[4];
  }
}

// K3: wave-per-row row chain. 4 rows/block, one 64-lane wave each, NO __syncthreads.
__global__ __launch_bounds__(256) void k_row(
    const float* __restrict__ S1, const float* __restrict__ S2,
    const float* __restrict__ fc1w, const float* __restrict__ fc1b,
    const float* __restrict__ fc2w, const float* __restrict__ fc2b,
    u16* __restrict__ adj, int b0)
{
  __shared__ u32 histS[4][256];
  const int tid = threadIdx.x;
  const int wv = tid >> 6;
  const int lane = tid & 63;
  const int n = blockIdx.x * 4 + wv;
  const int g = blockIdx.y;

  float w10[8], w11[8], b1s[8], w2s[8];
#pragma unroll
  for (int h = 0; h < 8; ++h) {
    w10[h] = fc1w[2 * h];
    w11[h] = fc1w[2 * h + 1];
    b1s[h] = fc1b[h];
    w2s[h] = fc2w[h];
  }
  const float b2s = fc2b[0];

  const float* r1 = S1 + ((size_t)g * 1024 + n) * 1024;
  const float* r2 = S2 + ((size_t)g * 1024 + n) * 1024;
  const int e0 = lane * 16;
  float s1v[16], s2v[16];
#pragma unroll
  for (int k = 0; k < 4; ++k) {
    *(float4*)&s1v[4 * k] = *(const float4*)&r1[e0 + 4 * k];
    *(float4*)&s2v[4 * k] = *(const float4*)&r2[e0 + 4 * k];
  }

  float lm1 = s1v[0], lm2 = s2v[0];
#pragma unroll
  for (int j = 1; j < 16; ++j) { lm1 = fmaxf(lm1, s1v[j]); lm2 = fmaxf(lm2, s2v[j]); }
  const float m1 = wredMaxF(lm1);
  const float m2 = wredMaxF(lm2);

  float e1[16], e2[16];
  double ls1 = 0.0, ls2 = 0.0;
#pragma unroll
  for (int j = 0; j < 16; ++j) {
    e1[j] = (float)exp((double)(s1v[j] - m1));
    ls1 += (double)e1[j];
    e2[j] = (float)exp((double)(s2v[j] - m2));
    ls2 += (double)e2[j];
  }
  const float Z1f = (float)wredSumD(ls1);
  const float Z2f = (float)wredSumD(ls2);

  float zv[16];
#pragma unroll
  for (int j = 0; j < 16; ++j) {
    float a1 = e1[j] / Z1f;
    float a2 = e2[j] / Z2f;
    float acc = 0.f;
#pragma unroll
    for (int h = 0; h < 8; ++h) {
      float hp = __fmaf_rn(a2, w11[h], __fmaf_rn(a1, w10[h], 0.0f));
      hp = hp + b1s[h];
      float hr = fmaxf(hp, 0.f);
      acc = __fmaf_rn(hr, w2s[h], acc);
    }
    zv[j] = acc + b2s;
  }

  float lmz = zv[0];
#pragma unroll
  for (int j = 1; j < 16; ++j) lmz = fmaxf(lmz, zv[j]);
  const float mz = wredMaxF(lmz);
  float ez[16];
  double lsz = 0.0;
#pragma unroll
  for (int j = 0; j < 16; ++j) {
    ez[j] = (float)exp((double)(zv[j] - mz));
    lsz += (double)ez[j];
  }
  const float Zzf = (float)wredSumD(lsz);

  u32 kreg[16];
#pragma unroll
  for (int j = 0; j < 16; ++j) kreg[j] = __float_as_uint(ez[j] / Zzf);

  volatile u32* hp = &histS[wv][0];
  u32 target = 819u;
  u32 prefix = 0u;
  for (int pass = 0; pass < 4; ++pass) {
    const int sh = 24 - 8 * pass;
#pragma unroll
    for (int i = 0; i < 4; ++i) hp[4 * lane + i] = 0u;
    wsync();
    if (pass == 0) {
#pragma unroll
      for (int j = 0; j < 16; ++j) {
        u32 bin = kreg[j] >> 24;
        bool pending = true;
        while (true) {
          u64 rem = __ballot(pending);
          if (rem == 0ull) break;
          int ld = (int)__ffsll((long long)rem) - 1;
          u32 fb = __shfl(bin, ld, 64);
          bool mine = pending && (bin == fb);
          u64 grp = __ballot(mine);
          if (lane == ld) atomicAdd((u32*)&hp[fb], (u32)__popcll(grp));
          if (mine) pending = false;
        }
      }
    } else {
#pragma unroll
      for (int j = 0; j < 16; ++j) {
        u32 key = kreg[j];
        if ((key >> (sh + 8)) == prefix) atomicAdd((u32*)&hp[(key >> sh) & 255u], 1u);
      }
    }
    wsync();
    u32 h0 = hp[4 * lane + 0], h1 = hp[4 * lane + 1];
    u32 h2 = hp[4 * lane + 2], h3 = hp[4 * lane + 3];
    u32 part = h0 + h1 + h2 + h3;
    u32 sfx = part;
#pragma unroll
    for (int o = 1; o < 64; o <<= 1) {
      u32 vsh = __shfl_down(sfx, o, 64);
      if (lane + o < 64) sfx += vsh;
    }
    u32 after = sfx - part;
    u32 c3 = h3 + after;
    u32 c2 = h2 + c3;
    u32 c1 = h1 + c2;
    u32 c0 = h0 + c1;
    u32 mybyte = 0u, myabove = 0u;
    bool found = false;
    if (c0 >= target && c1 < target)    { mybyte = (u32)(4 * lane + 0); myabove = c1; found = true; }
    if (c1 >= target && c2 < target)    { mybyte = (u32)(4 * lane + 1); myabove = c2; found = true; }
    if (c2 >= target && c3 < target)    { mybyte = (u32)(4 * lane + 2); myabove = c3; found = true; }
    if (c3 >= target && after < target) { mybyte = (u32)(4 * lane + 3); myabove = after; found = true; }
    u64 fb = __ballot(found);
    int src = (int)__ffsll((long long)fb) - 1;
    u32 byte_ = (u32)__shfl((int)mybyte, src, 64);
    u32 above = (u32)__shfl((int)myabove, src, 64);
    prefix = (prefix << 8) | byte_;
    target -= above;
    wsync();
  }
  const u32 vkey = prefix;
  const u32 need_eq = target;

  int cnt = 0;
#pragma unroll
  for (int j = 0; j < 16; ++j) cnt += (kreg[j] == vkey) ? 1 : 0;
  u32 inc = (u32)cnt;
#pragma unroll
  for (int o = 1; o < 64; o <<= 1) {
    u32 nv = __shfl_up(inc, o, 64);
    if (lane >= o) inc += nv;
  }
  u32 run = inc - (u32)cnt;

  u16 ov[16];
#pragma unroll
  for (int j = 0; j < 16; ++j) {
    u32 kk = kreg[j];
    bool eq = (kk == vkey);
    bool keep = (kk > vkey) || (eq && (run < need_eq));
    if (eq) run += 1u;
    ov[j] = keep ? f2bf(__uint_as_float(kk)) : (u16)0;
  }
  u16* arow = adj + ((size_t)(b0 + g) * 1024 + n) * 1024 + e0;
  *(uint4*)&arow[0] = *(uint4*)&ov[0];
  *(uint4*)&arow[8] = *(uint4*)&ov[8];
}

// K4: agg = adj @ vr, bf16 MFMA 16x16x32, 128x128 tile, BK=32
__global__ __launch_bounds__(256) void k_gemm_agg(
    const u16* __restrict__ adj, const u16* __restrict__ vrT, float* __restrict__ agg)
{
  __shared__ u16 As[128 * 40];
  __shared__ u16 Bs[128 * 40];
  const int tid = threadIdx.x;
  const int b = blockIdx.z;
  const int n0 = blockIdx.y * 128;
  const int ct0 = blockIdx.x * 128;
  const int wid = tid >> 6;
  const int lane = tid & 63;
  const int l16 = lane & 15;
  const int quad = lane >> 4;
  const int wm = (wid >> 1) * 64;
  const int wn = (wid & 1) * 64;

  f32x4 acc[4][4];
#pragma unroll
  for (int i = 0; i < 4; ++i)
#pragma unroll
    for (int j = 0; j < 4; ++j) acc[i][j] = (f32x4)0.f;

  const u16* aG = adj + ((size_t)b * 1024 + n0) * 1024;
  const u16* bG = vrT + ((size_t)b * 768 + ct0) * 1024;

  for (int kt = 0; kt < 32; ++kt) {
    const int k0 = kt * 32;
    __syncthreads();
#pragma unroll
    for (int j = 0; j < 2; ++j) {
      int idx = tid + 256 * j;
      int row = idx >> 2, seg = idx & 3;
      *(uint4*)&As[row * 40 + seg * 8] = *(const uint4*)&aG[(size_t)row * 1024 + k0 + seg * 8];
      *(uint4*)&Bs[row * 40 + seg * 8] = *(const uint4*)&bG[(size_t)row * 1024 + k0 + seg * 8];
    }
    __syncthreads();
    bf16x8 af[4], bfv[4];
#pragma unroll
    for (int i = 0; i < 4; ++i) af[i] = *(bf16x8*)&As[(wm + i * 16 + l16) * 40 + quad * 8];
#pragma unroll
    for (int j = 0; j < 4; ++j) bfv[j] = *(bf16x8*)&Bs[(wn + j * 16 + l16) * 40 + quad * 8];
#pragma unroll
    for (int i = 0; i < 4; ++i)
#pragma unroll
      for (int j = 0; j < 4; ++j)
        acc[i][j] = __builtin_amdgcn_mfma_f32_16x16x32_bf16(af[i], bfv[j], acc[i][j], 0, 0, 0);
  }

#pragma unroll
  for (int i = 0; i < 4; ++i)
#pragma unroll
    for (int j = 0; j < 4; ++j)
#pragma unroll
      for (int r = 0; r < 4; ++r) {
        int row = n0 + wm + i * 16 + quad * 4 + r;
        int col = ct0 + wn + j * 16 + l16;
        agg[((size_t)b * 1024 + row) * 768 + col] = acc[i][j][r];
      }
}

// K5: out = relu(conv_c(agg)), fp32
__global__ __launch_bounds__(256) void k_convc(
    const float* __restrict__ agg, const float* __restrict__ cw,
    const float* __restrict__ cb, float* __restrict__ out)
{
  __shared__ float aggL[16 * 388];
  __shared__ float cwT[64 * 68];
  __shared__ float cbL[64];
  const int tid = threadIdx.x;
  const int b = blockIdx.y;
  const int n0 = blockIdx.x * 16;

#pragma unroll
  for (int j = 0; j < 16; ++j) {
    int idx = tid + 256 * j;
    int o = idx >> 6, c = idx & 63;
    cwT[c * 68 + o] = cw[idx];
  }
  if (tid < 64) cbL[tid] = cb[tid];

  const int o0 = (tid & 15) * 4;
  const int nl = tid >> 4;
  float acc[4][12];
#pragma unroll
  for (int oo = 0; oo < 4; ++oo)
#pragma unroll
    for (int t = 0; t < 12; ++t) acc[oo][t] = 0.f;

  for (int ph = 0; ph < 2; ++ph) {
    __syncthreads();
#pragma unroll
    for (int j = 0; j < 6; ++j) {
      int q4 = tid + 256 * j;
      int row = q4 / 96, wi = q4 - row * 96;
      *(float4*)&aggL[row * 388 + wi * 4] =
          *(const float4*)&agg[((size_t)(b * 1024 + n0 + row)) * 768 + ph * 384 + wi * 4];
    }
    __syncthreads();
    for (int cc = 0; cc < 32; ++cc) {
      int c = ph * 32 + cc;
      float4 w4 = *(float4*)&cwT[c * 68 + o0];
      float xr[12];
      *(float4*)&xr[0] = *(float4*)&aggL[nl * 388 + cc * 12 + 0];
      *(float4*)&xr[4] = *(float4*)&aggL[nl * 388 + cc * 12 + 4];
      *(float4*)&xr[8] = *(float4*)&aggL[nl * 388 + cc * 12 + 8];
#pragma unroll
      for (int t = 0; t < 12; ++t) {
        acc[0][t] += w4.x * xr[t];
        acc[1][t] += w4.y * xr[t];
        acc[2][t] += w4.z * xr[t];
        acc[3][t] += w4.w * xr[t];
      }
    }
  }

#pragma unroll
  for (int oo = 0; oo < 4; ++oo) {
    int o = o0 + oo;
    float bias = cbL[o];
    float ovv[12];
#pragma unroll
    for (int t = 0; t < 12; ++t) ovv[t] = fmaxf(acc[oo][t] + bias, 0.f);
    size_t base = ((size_t)(b * 64 + o) * 1024 + n0 + nl) * 12;
    *(float4*)&out[base + 0] = *(float4*)&ovv[0];
    *(float4*)&out[base + 4] = *(float4*)&ovv[4];
    *(float4*)&out[base + 8] = *(float4*)&ovv[8];
  }
}

extern "C" void kernel_launch(void* const* d_in, const int* in_sizes, int n_in,
                              void* d_out, int out_size, void* d_ws, size_t ws_size,
                              hipStream_t stream)
{
  const float* x    = (const float*)d_in[0];
  const float* qw   = (const float*)d_in[1];
  const float* qb   = (const float*)d_in[2];
  const float* vw   = (const float*)d_in[3];
  const float* vb   = (const float*)d_in[4];
  const float* cw   = (const float*)d_in[5];
  const float* cb   = (const float*)d_in[6];
  const float* mem  = (const float*)d_in[7];
  const float* fc1w = (const float*)d_in[8];
  const float* fc1b = (const float*)d_in[9];
  const float* fc2w = (const float*)d_in[10];
  const float* fc2b = (const float*)d_in[11];
  float* out = (float*)d_out;
  char* ws = (char*)d_ws;

  const size_t szQS64  = (size_t)16 * 1024 * 64 * 8;   // 8 MB
  const size_t szQS32T = (size_t)16 * 1024 * 64 * 4;   // 4 MB
  const size_t szVR    = (size_t)16 * 1024 * 768 * 2;  // 24 MB
  const size_t szADJ   = (size_t)16 * 1024 * 1024 * 2; // 32 MB
  const size_t szAGG   = (size_t)16 * 1024 * 768 * 4;  // 48 MB
  const size_t szSb    = (size_t)1024 * 1024 * 4;      // one f32 S matrix, one batch
  const size_t fixed   = szQS64 + szQS32T + 2 * szVR + szADJ + szAGG;  // 140 MB

  int G = 16;
  while (G > 1 && (fixed + (size_t)2 * G * szSb) > ws_size) G >>= 1;

  double* qs64  = (double*)(ws);
  float*  qs32T = (float*)(ws + szQS64);
  u16*  vr      = (u16*)(ws + szQS64 + szQS32T);
  u16*  vrT     = (u16*)(ws + szQS64 + szQS32T + szVR);
  u16*  adj     = (u16*)(ws + szQS64 + szQS32T + 2 * szVR);
  float* agg    = (float*)(ws + szQS64 + szQS32T + 2 * szVR + szADJ);
  float* S1     = (float*)(ws + fixed);
  float* S2     = S1 + (size_t)G * 1024 * 1024;

  hipLaunchKernelGGL(k_conv_qv, dim3(128, 16), dim3(256), 0, stream, x, qw, qb, vw, vb, qs64, qs32T, vr);
  hipLaunchKernelGGL(k_transpose_vr, dim3(12, 16, 16), dim3(256), 0, stream, vr, vrT);
  for (int b0 = 0; b0 < 16; b0 += G) {
    hipLaunchKernelGGL(k_score, dim3(16, 8, G), dim3(256), 0, stream, qs64, qs32T, mem, S1, S2, b0);
    hipLaunchKernelGGL(k_row, dim3(256, G), dim3(256), 0, stream, S1, S2, fc1w, fc1b, fc2w, fc2b, adj, b0);
  }
  hipLaunchKernelGGL(k_gemm_agg, dim3(6, 8, 16), dim3(256), 0, stream, adj, vrT, agg);
  hipLaunchKernelGGL(k_convc, dim3(64, 16), dim3(256), 0, stream, agg, cw, cb, out);
}